// Round 1
// baseline (319.657 us; speedup 1.0000x reference)
//
#include <hip/hip_runtime.h>
#include <hip/hip_bf16.h>
#include <stdint.h>

// Problem constants (from reference setup_inputs)
#define NN 128
#define TT 64
#define CC 6625
#define SS 25
#define SE 51          // 2*S+1
#define LPW 26         // blank + 25 labels stored per (n,t)
#define NEGV (-1e30f)

// ---------------------------------------------------------------------------
// Kernel 1: per-(n,t) row logsumexp over C=6625 + gather of 26 needed classes
// lp[(n*T+t)*26 + j] = logits[n,t,cls_j] - logsumexp_c(logits[n,t,:])
//   j==0 -> blank (class 0); j>0 -> targets[n, j-1]
// ---------------------------------------------------------------------------
__global__ __launch_bounds__(256) void lse_gather_kernel(
    const float* __restrict__ logits,
    const int*   __restrict__ targets,
    float*       __restrict__ lp)
{
    const int row = blockIdx.x;              // n*T + t
    const int tid = threadIdx.x;
    const float* __restrict__ x = logits + (size_t)row * CC;

    // Alignment: rows shift by 4 bytes each row (C odd). Find aligned body.
    const int mis  = (int)(((uintptr_t)x) & 15u) >> 2;   // elements into 16B
    const int head = (4 - mis) & 3;
    const int nvec = (CC - head) >> 2;
    const int tail = head + (nvec << 2);

    // 4 independent online (m,s) accumulators to cut exp dependency chains.
    float m0 = NEGV, m1 = NEGV, m2 = NEGV, m3 = NEGV;
    float s0 = 0.f,  s1 = 0.f,  s2 = 0.f,  s3 = 0.f;

#define UPD(mm, ss, vv)                              \
    do {                                             \
        float _v = (vv);                             \
        if (_v > mm) {                               \
            ss = ss * __expf(mm - _v) + 1.f;         \
            mm = _v;                                 \
        } else {                                     \
            ss += __expf(_v - mm);                   \
        }                                            \
    } while (0)

    // head scalars
    for (int i = tid; i < head; i += 256) UPD(m0, s0, x[i]);
    // aligned float4 body
    const float4* __restrict__ xv = reinterpret_cast<const float4*>(x + head);
    for (int i = tid; i < nvec; i += 256) {
        float4 v = xv[i];
        UPD(m0, s0, v.x);
        UPD(m1, s1, v.y);
        UPD(m2, s2, v.z);
        UPD(m3, s3, v.w);
    }
    // tail scalars
    for (int i = tail + tid; i < CC; i += 256) UPD(m0, s0, x[i]);

    // merge the 4 accumulators
    float m = fmaxf(fmaxf(m0, m1), fmaxf(m2, m3));
    float s = s0 * __expf(m0 - m) + s1 * __expf(m1 - m) +
              s2 * __expf(m2 - m) + s3 * __expf(m3 - m);

    // wave-level (m,s) reduce (64 lanes)
    for (int off = 1; off < 64; off <<= 1) {
        float om = __shfl_xor(m, off, 64);
        float os = __shfl_xor(s, off, 64);
        float nm = fmaxf(m, om);
        s = s * __expf(m - nm) + os * __expf(om - nm);
        m = nm;
    }

    __shared__ float sm[4], ssv[4];
    __shared__ float lse_sh;
    const int wid = tid >> 6;
    if ((tid & 63) == 0) { sm[wid] = m; ssv[wid] = s; }
    __syncthreads();
    if (tid == 0) {
        float M = sm[0], SSum = ssv[0];
        for (int w = 1; w < 4; ++w) {
            float nm = fmaxf(M, sm[w]);
            SSum = SSum * __expf(M - nm) + ssv[w] * __expf(sm[w] - nm);
            M = nm;
        }
        lse_sh = M + __logf(SSum);
    }
    __syncthreads();
    const float lse = lse_sh;

    if (tid < LPW) {
        const int n   = row / TT;
        const int cls = (tid == 0) ? 0 : targets[n * SS + tid - 1];
        lp[(size_t)row * LPW + tid] = x[cls] - lse;
    }
#undef UPD
}

// ---------------------------------------------------------------------------
// Kernel 2: CTC alpha recursion, one wave per sample, lane = extended state.
// ---------------------------------------------------------------------------
__global__ __launch_bounds__(64) void ctc_alpha_kernel(
    const float* __restrict__ lp,
    const int*   __restrict__ targets,
    const int*   __restrict__ target_length,
    float*       __restrict__ sample_loss)
{
    const int n = blockIdx.x;
    const int s = threadIdx.x;                 // lane = state index
    const bool active = (s < SE);

    // gather position inside the 26-wide lp row: even state -> blank (0),
    // odd state s -> label index (s-1)/2 -> slot 1 + (s>>1)
    const int pos = (s & 1) ? (1 + (s >> 1)) : 0;

    // can_skip: s odd (label != blank) and label != label two states back
    bool can_skip = false;
    if (active && (s & 1)) {
        if (s == 1) can_skip = true;
        else {
            const int lab  = targets[n * SS + (s >> 1)];
            const int lab2 = targets[n * SS + (s >> 1) - 1];
            can_skip = (lab != lab2);
        }
    }

    const float* __restrict__ lpn = lp + (size_t)n * TT * LPW;

    float alpha = NEGV;
    {
        const float lp0 = active ? lpn[pos] : NEGV;
        if (s < 2) alpha = lp0;
    }

    for (int t = 1; t < TT; ++t) {
        const float a1 = alpha;
        float a2 = __shfl_up(alpha, 1, 64);
        if (s == 0) a2 = NEGV;
        float a3 = __shfl_up(alpha, 2, 64);
        if (s < 2 || !can_skip) a3 = NEGV;
        const float mx  = fmaxf(a1, fmaxf(a2, a3));
        const float sum = __expf(a1 - mx) + __expf(a2 - mx) + __expf(a3 - mx);
        const float lpt = active ? lpn[t * LPW + pos] : NEGV;
        float na = mx + __logf(sum) + lpt;
        alpha = active ? na : NEGV;
    }

    int L = target_length[n];
    L = (L < 1) ? 1 : ((L > SS) ? SS : L);     // values are in [1,S] anyway
    const float aL1 = __shfl(alpha, 2 * L - 1, 64);
    const float aL2 = __shfl(alpha, 2 * L,     64);
    if (s == 0) {
        const float mx = fmaxf(aL1, aL2);
        const float ll = mx + __logf(__expf(aL1 - mx) + __expf(aL2 - mx));
        const float loss = -ll;
        const float w = 1.f - __expf(-loss);   // focal weight, GAMMA=2, ALPHA=1
        sample_loss[n] = loss * w * w;
    }
}

// ---------------------------------------------------------------------------
// Kernel 3: mean over N=128 samples
// ---------------------------------------------------------------------------
__global__ __launch_bounds__(128) void reduce_kernel(
    const float* __restrict__ sample_loss, float* __restrict__ out)
{
    float v = sample_loss[threadIdx.x];
    for (int off = 1; off < 64; off <<= 1) v += __shfl_xor(v, off, 64);
    __shared__ float tmp[2];
    if ((threadIdx.x & 63) == 0) tmp[threadIdx.x >> 6] = v;
    __syncthreads();
    if (threadIdx.x == 0) out[0] = (tmp[0] + tmp[1]) * (1.0f / NN);
}

// ---------------------------------------------------------------------------
extern "C" void kernel_launch(void* const* d_in, const int* in_sizes, int n_in,
                              void* d_out, int out_size, void* d_ws, size_t ws_size,
                              hipStream_t stream)
{
    const float* logits  = (const float*)d_in[0];   // [N,T,C] f32
    const int*   targets = (const int*)  d_in[1];   // [N,S]   i32
    const int*   tlen    = (const int*)  d_in[2];   // [N]     i32
    float*       out     = (float*)d_out;           // scalar

    float* lp          = (float*)d_ws;              // N*T*26 floats (852 KB)
    float* sample_loss = lp + (size_t)NN * TT * LPW;

    lse_gather_kernel<<<NN * TT, 256, 0, stream>>>(logits, targets, lp);
    ctc_alpha_kernel<<<NN, 64, 0, stream>>>(lp, targets, tlen, sample_loss);
    reduce_kernel<<<1, 128, 0, stream>>>(sample_loss, out);
}

// Round 2
// 307.487 us; speedup vs baseline: 1.0396x; 1.0396x over previous
//
#include <hip/hip_runtime.h>
#include <hip/hip_bf16.h>
#include <stdint.h>

// Problem constants (from reference setup_inputs)
#define NN 128
#define TT 64
#define CC 6625
#define SS 25
#define SE 51          // 2*S+1
#define LPW 26         // blank + 25 labels stored per (n,t)
#define NEGV (-1e30f)

// ---------------------------------------------------------------------------
// Kernel 1: per-(n,t) row logsumexp over C=6625 + gather of 26 needed classes.
// Two-phase, register-resident: load 26 elems/thread into regs (pad NEGV),
// block max-reduce, one exp per element, block sum-reduce.
// lp[(n*T+t)*26 + j] = logits[n,t,cls_j] - lse(row)
// ---------------------------------------------------------------------------
__global__ __launch_bounds__(256) void lse_gather_kernel(
    const float* __restrict__ logits,
    const int*   __restrict__ targets,
    float*       __restrict__ lp)
{
    const int row = blockIdx.x;              // n*T + t
    const int tid = threadIdx.x;
    const float* __restrict__ x = logits + (size_t)row * CC;

    // rows shift by 4 B each (C odd) — find the 16B-aligned body
    const int mis  = (int)(((uintptr_t)x) & 15u) >> 2;
    const int head = (4 - mis) & 3;                 // 0..3 scalars before body
    const int nvec = (CC - head) >> 2;              // 1655 or 1656 float4s
    const int tail = head + (nvec << 2);            // first scalar after body

    const float4* __restrict__ xv = reinterpret_cast<const float4*>(x + head);

    // ---- phase 0: load everything into registers (pad with NEGV) ----
    float4 v[7];
#pragma unroll
    for (int k = 0; k < 7; ++k) {
        const int i = tid + (k << 8);
        if (i < nvec) v[k] = xv[i];
        else          v[k] = make_float4(NEGV, NEGV, NEGV, NEGV);
    }
    const float e0 = (tid < head)       ? x[tid]        : NEGV;  // head scalars
    const float e1 = (tail + tid < CC)  ? x[tail + tid] : NEGV;  // tail scalars

    // ---- phase 1: block max ----
    float m = fmaxf(e0, e1);
#pragma unroll
    for (int k = 0; k < 7; ++k) {
        m = fmaxf(m, fmaxf(fmaxf(v[k].x, v[k].y), fmaxf(v[k].z, v[k].w)));
    }
#pragma unroll
    for (int off = 1; off < 64; off <<= 1)
        m = fmaxf(m, __shfl_xor(m, off, 64));

    __shared__ float sm[4];
    __shared__ float ssv[4];
    const int wid = tid >> 6;
    if ((tid & 63) == 0) sm[wid] = m;
    __syncthreads();
    const float M = fmaxf(fmaxf(sm[0], sm[1]), fmaxf(sm[2], sm[3]));

    // ---- phase 2: block sum of exp(v - M) (padded slots contribute 0) ----
    float s = __expf(e0 - M) + __expf(e1 - M);
#pragma unroll
    for (int k = 0; k < 7; ++k) {
        s += __expf(v[k].x - M) + __expf(v[k].y - M) +
             __expf(v[k].z - M) + __expf(v[k].w - M);
    }
#pragma unroll
    for (int off = 1; off < 64; off <<= 1)
        s += __shfl_xor(s, off, 64);
    if ((tid & 63) == 0) ssv[wid] = s;
    __syncthreads();
    const float S   = ssv[0] + ssv[1] + ssv[2] + ssv[3];
    const float lse = M + __logf(S);

    // ---- gather the 26 needed classes ----
    if (tid < LPW) {
        const int n   = row / TT;
        const int cls = (tid == 0) ? 0 : targets[n * SS + tid - 1];
        lp[(size_t)row * LPW + tid] = x[cls] - lse;
    }
}

// ---------------------------------------------------------------------------
// Kernel 2: CTC alpha recursion (one wave per sample, lane = state) + focal
// weighting + atomic mean into d_out. lp preloaded into registers so the
// 64-step chain is pure shuffle+ALU.
// ---------------------------------------------------------------------------
__global__ __launch_bounds__(64) void ctc_alpha_kernel(
    const float* __restrict__ lp,
    const int*   __restrict__ targets,
    const int*   __restrict__ target_length,
    float*       __restrict__ out)
{
    const int n = blockIdx.x;
    const int s = threadIdx.x;                 // lane = extended-state index
    const bool active = (s < SE);

    // slot in the 26-wide lp row: even state -> blank(0), odd -> 1 + s/2
    const int pos = (s & 1) ? (1 + (s >> 1)) : 0;

    bool can_skip = false;
    if (active && (s & 1)) {
        if (s == 1) can_skip = true;
        else {
            const int lab  = targets[n * SS + (s >> 1)];
            const int lab2 = targets[n * SS + (s >> 1) - 1];
            can_skip = (lab != lab2);
        }
    }

    const float* __restrict__ lpn = lp + (size_t)n * TT * LPW;

    // preload all T log-probs for this lane's state (loads are independent)
    float lpt[TT];
#pragma unroll
    for (int t = 0; t < TT; ++t)
        lpt[t] = active ? lpn[t * LPW + pos] : NEGV;

    float alpha = (s < 2) ? lpt[0] : NEGV;

#pragma unroll
    for (int t = 1; t < TT; ++t) {
        const float a1 = alpha;
        float a2 = __shfl_up(alpha, 1, 64);
        if (s == 0) a2 = NEGV;
        float a3 = __shfl_up(alpha, 2, 64);
        if (s < 2 || !can_skip) a3 = NEGV;
        const float mx  = fmaxf(a1, fmaxf(a2, a3));
        const float sum = __expf(a1 - mx) + __expf(a2 - mx) + __expf(a3 - mx);
        alpha = active ? (mx + __logf(sum) + lpt[t]) : NEGV;
    }

    int L = target_length[n];
    L = (L < 1) ? 1 : ((L > SS) ? SS : L);
    const float aL1 = __shfl(alpha, 2 * L - 1, 64);
    const float aL2 = __shfl(alpha, 2 * L,     64);
    if (s == 0) {
        const float mx = fmaxf(aL1, aL2);
        const float ll = mx + __logf(__expf(aL1 - mx) + __expf(aL2 - mx));
        const float loss = -ll;
        const float w = 1.f - __expf(-loss);   // focal, GAMMA=2, ALPHA=1
        atomicAdd(out, loss * w * w * (1.0f / NN));
    }
}

// ---------------------------------------------------------------------------
extern "C" void kernel_launch(void* const* d_in, const int* in_sizes, int n_in,
                              void* d_out, int out_size, void* d_ws, size_t ws_size,
                              hipStream_t stream)
{
    const float* logits  = (const float*)d_in[0];   // [N,T,C] f32
    const int*   targets = (const int*)  d_in[1];   // [N,S]   i32
    const int*   tlen    = (const int*)  d_in[2];   // [N]     i32
    float*       out     = (float*)d_out;           // scalar

    float* lp = (float*)d_ws;                       // N*T*26 floats (852 KB)

    hipMemsetAsync(out, 0, sizeof(float) * out_size, stream);
    lse_gather_kernel<<<NN * TT, 256, 0, stream>>>(logits, targets, lp);
    ctc_alpha_kernel<<<NN, 64, 0, stream>>>(lp, targets, tlen, out);
}